// Round 9
// baseline (235.155 us; speedup 1.0000x reference)
//
#include <hip/hip_runtime.h>
#include <math.h>

#define NN   24          // nodes per graph
#define EPB  16          // graph elements per block
#define CSTR 28          // LDS column stride (floats): 24 + 4 pad, 16B aligned
#define ESTR 452         // per-elem stride: 16*28 + 4 → e-stride ≡ 4 banks mod 32
#define T    256

// ws layout (floats): [0..575] A(24x24) | [576..2111] Wc(768x2) | [2112..2113] bc(2)

__global__ void prep_kernel(const int* __restrict__ ei, int ec,
                            const float* __restrict__ fcw1, const float* __restrict__ fcb1,
                            const float* __restrict__ fcw2, const float* __restrict__ fcb2,
                            float* __restrict__ ws) {
  int t = threadIdx.x;
  if (blockIdx.x == 0) {
    __shared__ float deg[NN];
    __shared__ float dinv[NN];
    __shared__ float As[NN*NN];
    __shared__ int s_is64;
    if (t == 0) s_is64 = 1;
    if (t < NN) deg[t] = 1.0f;            // self-loop contribution
    for (int k = t; k < NN*NN; k += T) As[k] = 0.0f;
    __syncthreads();
    // dtype sniff: int64 edge_index viewed as int32 has all odd (high) words == 0
    for (int k = t; k < 2*ec; k += T) {
      if (ei[2*k + 1] != 0) atomicExch(&s_is64, 0);
    }
    __syncthreads();
    int is64 = s_is64;
    for (int k = t; k < ec; k += T) {
      int d = is64 ? ei[2*(ec + k)] : ei[ec + k];
      atomicAdd(&deg[d], 1.0f);
    }
    __syncthreads();
    if (t < NN) dinv[t] = 1.0f / sqrtf(deg[t]);
    __syncthreads();
    for (int k = t; k < ec; k += T) {
      int s = is64 ? ei[2*k]        : ei[k];
      int d = is64 ? ei[2*(ec + k)] : ei[ec + k];
      atomicAdd(&As[d*NN + s], dinv[s]*dinv[d]);
    }
    if (t < NN) atomicAdd(&As[t*NN + t], dinv[t]*dinv[t]);  // self loop
    __syncthreads();
    for (int k = t; k < NN*NN; k += T) ws[k] = As[k];
    if (t < 2) {
      float acc = fcb2[t];
      for (int k = 0; k < 128; ++k) acc += fcb1[k]*fcw2[k*2 + t];
      ws[2112 + t] = acc;
    }
  } else {
    // Wc = fcw1 @ fcw2 : blocks 1..8 compute 96 rows each
    int r0 = (blockIdx.x - 1) * 96;
    for (int idx = t; idx < 96*2; idx += T) {
      int r = r0 + (idx >> 1), c = idx & 1;
      float acc = 0.f;
      for (int k = 0; k < 128; ++k) acc += fcw1[r*128 + k]*fcw2[k*2 + c];
      ws[576 + r*2 + c] = acc;
    }
  }
}

// Merged step: gbuf holds g_l = A @ h_{l-1} (FIN cols per elem).
// Thread (e, f, chunk): h_l col f = relu(g_l @ W + b), BARRIER (all gbuf reads
// done), then per row-pair: A-mix with A rows streamed as float4 (wave-uniform
// address → scalar-load eligible) → immediate float2 write in place.
// Peak live ≈ hh[24] + 8 A-floats + 2 acc ≈ 34 floats: spill-free even at the
// allocator's habitual 56-64 VGPR choice.
template<int FIN, int FOUT, int SPLIT>
__device__ __forceinline__ void merged_layer(const float* __restrict__ Ag, float* gbuf,
                                             const float* Ws, const float* bs, int t) {
  constexpr int NCOLS = EPB*FOUT;       // 64/64/128/128/256/256
  constexpr int CL    = NN/SPLIT;       // 6/6/12/12/24/24
  int col = t & (NCOLS - 1);
  int i0  = __builtin_amdgcn_readfirstlane((t / NCOLS) * CL);  // wave-uniform
  int e = col / FOUT;
  int f = col & (FOUT - 1);
  const float* ib = gbuf + e*ESTR;
  // W-mix: full column of h_l in registers, seeded with bias
  float bf = bs[f];
  float hh[NN];
  #pragma unroll
  for (int i = 0; i < NN; ++i) hh[i] = bf;
  #pragma unroll
  for (int fi = 0; fi < FIN; ++fi) {
    float w = Ws[fi*FOUT + f];
    const float4* c4 = (const float4*)(ib + fi*CSTR);
    #pragma unroll
    for (int k = 0; k < 6; ++k) {
      float4 v = c4[k];
      hh[4*k+0] += v.x*w; hh[4*k+1] += v.y*w; hh[4*k+2] += v.z*w; hh[4*k+3] += v.w*w;
    }
  }
  #pragma unroll
  for (int i = 0; i < NN; ++i) hh[i] = fmaxf(hh[i], 0.f);
  __syncthreads();           // all gbuf reads complete before in-place overwrite
  // A-mix row-pair → write immediately; A rows as float4 (24 floats = 6/row)
  float* ob = gbuf + e*ESTR + f*CSTR + i0;
  #pragma unroll
  for (int ii = 0; ii < CL; ii += 2) {
    const float4* ArA = (const float4*)(Ag + (i0 + ii)*NN);
    const float4* ArB = (const float4*)(Ag + (i0 + ii + 1)*NN);
    float a0 = 0.f, a1 = 0.f;
    #pragma unroll
    for (int k = 0; k < 6; ++k) {
      float4 va = ArA[k], vb = ArB[k];
      a0 += va.x*hh[4*k] + va.y*hh[4*k+1] + va.z*hh[4*k+2] + va.w*hh[4*k+3];
      a1 += vb.x*hh[4*k] + vb.y*hh[4*k+1] + vb.z*hh[4*k+2] + vb.w*hh[4*k+3];
    }
    *(float2*)(ob + ii) = make_float2(a0, a1);
  }
}

__global__ __launch_bounds__(256, 4) void gcn_main(
    const float* __restrict__ x, const float* __restrict__ ws,
    const float* __restrict__ W1, const float* __restrict__ b1,
    const float* __restrict__ W2, const float* __restrict__ b2,
    const float* __restrict__ W3, const float* __restrict__ b3,
    const float* __restrict__ W4, const float* __restrict__ b4,
    const float* __restrict__ W5, const float* __restrict__ b5,
    const float* __restrict__ W6, const float* __restrict__ b6,
    const float* __restrict__ W7, const float* __restrict__ b7,
    float* __restrict__ out) {
  __shared__ __align__(16) float gbuf[EPB*ESTR];  // 28928 B, single in-place buffer
  __shared__ float Wsh[500];                      // W1..W6; W7 read from global/L1
  __shared__ __align__(16) float bsh[88];
  int t = threadIdx.x;

  // stage layer weights/biases into LDS
  {
    const float* Wp[6] = {W1,W2,W3,W4,W5,W6};
    const float* bp[7] = {b1,b2,b3,b4,b5,b6,b7};
    const int wsz[6] = {4,16,32,64,128,256};
    const int wof[6] = {0,4,20,52,116,244};
    const int bsz[7] = {4,4,8,8,16,16,32};
    const int bof[7] = {0,4,8,16,24,40,56};
    #pragma unroll
    for (int l = 0; l < 6; ++l) {
      for (int k = t; k < wsz[l]; k += T) Wsh[wof[l] + k] = Wp[l][k];
    }
    #pragma unroll
    for (int l = 0; l < 7; ++l) {
      if (t < bsz[l]) bsh[bof[l] + t] = bp[l][t];
    }
  }
  // stage x tile into column slot 1 of each elem (col 0 gets g1 = A@x)
  {
    const float* xg = x + (size_t)blockIdx.x * (EPB*NN);
    if (t < EPB*NN/4) {
      float4 v = ((const float4*)xg)[t];
      int e = t/6, k = t - e*6;
      ((float4*)(gbuf + e*ESTR + CSTR))[k] = v;
    }
  }
  __syncthreads();

  // g1 = A @ x : 384 tasks (e, i); A rows per-lane from global (2.3 KB, L1-hot)
  {
    int e = t & 15, i = t >> 4;          // i in 0..15
    const float4* xv = (const float4*)(gbuf + e*ESTR + CSTR);
    const float4* Ar = (const float4*)(ws + i*NN);
    float acc = 0.f;
    #pragma unroll
    for (int k = 0; k < 6; ++k) {
      float4 a = Ar[k]; float4 v = xv[k];
      acc += a.x*v.x + a.y*v.y + a.z*v.z + a.w*v.w;
    }
    gbuf[e*ESTR + i] = acc;
    if (t < 128) {
      int i2 = 16 + (t >> 4);            // i in 16..23
      const float4* Ar2 = (const float4*)(ws + i2*NN);
      float acc2 = 0.f;
      #pragma unroll
      for (int k = 0; k < 6; ++k) {
        float4 a = Ar2[k]; float4 v = xv[k];
        acc2 += a.x*v.x + a.y*v.y + a.z*v.z + a.w*v.w;
      }
      gbuf[e*ESTR + i2] = acc2;
    }
  }
  __syncthreads();

  merged_layer<1, 4, 4>(ws, gbuf, Wsh+0,   bsh+0,  t); __syncthreads();
  merged_layer<4, 4, 4>(ws, gbuf, Wsh+4,   bsh+4,  t); __syncthreads();
  merged_layer<4, 8, 2>(ws, gbuf, Wsh+20,  bsh+8,  t); __syncthreads();
  merged_layer<8, 8, 2>(ws, gbuf, Wsh+52,  bsh+16, t); __syncthreads();
  merged_layer<8,16, 1>(ws, gbuf, Wsh+116, bsh+24, t); __syncthreads();
  merged_layer<16,16,1>(ws, gbuf, Wsh+244, bsh+40, t); __syncthreads();

  // L7 + composed FC + log_softmax. Column task (e,f) as in R5, but the 24-row
  // column is processed in TWO 12-row passes so only hh[12] is ever live —
  // keeps the kernel's global VGPR pressure peak under the allocator's budget
  // (the 24/48-float epilogue arrays were what forced whole-kernel spilling).
  {
    const float* Wc = ws + 576;
    float bc0 = ws[2112], bc1 = ws[2113];
    #pragma unroll
    for (int r = 0; r < 2; ++r) {
      int col = t + r*T;               // 512 columns = 16 elems x 32 feats
      int e = col >> 5, f = col & 31;
      const float* ib = gbuf + e*ESTR;
      float bf = bsh[56 + f];
      float p0 = 0.f, p1 = 0.f;
      #pragma unroll
      for (int half = 0; half < 2; ++half) {
        float hh[12];
        #pragma unroll
        for (int i = 0; i < 12; ++i) hh[i] = bf;
        #pragma unroll
        for (int fi = 0; fi < 16; ++fi) {
          float w = W7[fi*32 + f];     // global, L1-cached, coalesced
          const float4* c4 = (const float4*)(ib + fi*CSTR + half*12);
          #pragma unroll
          for (int k = 0; k < 3; ++k) {
            float4 v = c4[k];
            hh[4*k+0] += v.x*w; hh[4*k+1] += v.y*w; hh[4*k+2] += v.z*w; hh[4*k+3] += v.w*w;
          }
        }
        #pragma unroll
        for (int i = 0; i < 12; ++i) {
          float hr = fmaxf(hh[i], 0.f);
          float2 wc = *(const float2*)(Wc + ((half*12 + i)*32 + f)*2);
          p0 += hr*wc.x; p1 += hr*wc.y;
        }
      }
      #pragma unroll
      for (int m = 1; m < 32; m <<= 1) {
        p0 += __shfl_xor(p0, m, 32);
        p1 += __shfl_xor(p1, m, 32);
      }
      if (f < 2) {
        float z0 = p0 + bc0, z1 = p1 + bc1;
        float mx = fmaxf(z0, z1);
        float lse = mx + logf(expf(z0 - mx) + expf(z1 - mx));
        int eg = blockIdx.x*EPB + e;
        out[eg*2 + f] = (f == 0 ? z0 : z1) - lse;
      }
    }
  }
}

extern "C" void kernel_launch(void* const* d_in, const int* in_sizes, int n_in,
                              void* d_out, int out_size, void* d_ws, size_t ws_size,
                              hipStream_t stream) {
  const float* x    = (const float*)d_in[0];
  const int*   ei   = (const int*)  d_in[1];
  const float* W1   = (const float*)d_in[2];  const float* b1 = (const float*)d_in[3];
  const float* W2   = (const float*)d_in[4];  const float* b2 = (const float*)d_in[5];
  const float* W3   = (const float*)d_in[6];  const float* b3 = (const float*)d_in[7];
  const float* W4   = (const float*)d_in[8];  const float* b4 = (const float*)d_in[9];
  const float* W5   = (const float*)d_in[10]; const float* b5 = (const float*)d_in[11];
  const float* W6   = (const float*)d_in[12]; const float* b6 = (const float*)d_in[13];
  const float* W7   = (const float*)d_in[14]; const float* b7 = (const float*)d_in[15];
  const float* fcw1 = (const float*)d_in[16]; const float* fcb1 = (const float*)d_in[17];
  const float* fcw2 = (const float*)d_in[18]; const float* fcb2 = (const float*)d_in[19];
  float* out = (float*)d_out;
  float* ws  = (float*)d_ws;
  int ec = in_sizes[1] / 2;        // 96 edges
  int B  = in_sizes[0] / NN;       // 32768

  hipLaunchKernelGGL(prep_kernel, dim3(9), dim3(T), 0, stream,
                     ei, ec, fcw1, fcb1, fcw2, fcb2, ws);
  hipLaunchKernelGGL(gcn_main, dim3(B/EPB), dim3(T), 0, stream,
                     x, ws, W1,b1, W2,b2, W3,b3, W4,b4, W5,b5, W6,b6, W7,b7, out);
}

// Round 10
// 206.804 us; speedup vs baseline: 1.1371x; 1.1371x over previous
//
#include <hip/hip_runtime.h>
#include <math.h>

#define NN   24          // nodes per graph
#define EPB  16          // graph elements per block
#define CSTR 28          // LDS column stride (floats): 24 + 4 pad, 16B aligned
#define ESTR 452         // per-elem stride: 16*28 + 4 → e-stride ≡ 4 banks mod 32
#define T    256

typedef float v2f __attribute__((ext_vector_type(2)));

// ws layout (floats): [0..575] A(24x24) | [576..2111] Wc(768x2) | [2112..2113] bc(2)

__global__ void prep_kernel(const int* __restrict__ ei, int ec,
                            const float* __restrict__ fcw1, const float* __restrict__ fcb1,
                            const float* __restrict__ fcw2, const float* __restrict__ fcb2,
                            float* __restrict__ ws) {
  int t = threadIdx.x;
  if (blockIdx.x == 0) {
    __shared__ float deg[NN];
    __shared__ float dinv[NN];
    __shared__ float As[NN*NN];
    __shared__ int s_is64;
    if (t == 0) s_is64 = 1;
    if (t < NN) deg[t] = 1.0f;            // self-loop contribution
    for (int k = t; k < NN*NN; k += T) As[k] = 0.0f;
    __syncthreads();
    // dtype sniff: int64 edge_index viewed as int32 has all odd (high) words == 0
    for (int k = t; k < 2*ec; k += T) {
      if (ei[2*k + 1] != 0) atomicExch(&s_is64, 0);
    }
    __syncthreads();
    int is64 = s_is64;
    for (int k = t; k < ec; k += T) {
      int d = is64 ? ei[2*(ec + k)] : ei[ec + k];
      atomicAdd(&deg[d], 1.0f);
    }
    __syncthreads();
    if (t < NN) dinv[t] = 1.0f / sqrtf(deg[t]);
    __syncthreads();
    for (int k = t; k < ec; k += T) {
      int s = is64 ? ei[2*k]        : ei[k];
      int d = is64 ? ei[2*(ec + k)] : ei[ec + k];
      atomicAdd(&As[d*NN + s], dinv[s]*dinv[d]);
    }
    if (t < NN) atomicAdd(&As[t*NN + t], dinv[t]*dinv[t]);  // self loop
    __syncthreads();
    for (int k = t; k < NN*NN; k += T) ws[k] = As[k];
    if (t < 2) {
      float acc = fcb2[t];
      for (int k = 0; k < 128; ++k) acc += fcb1[k]*fcw2[k*2 + t];
      ws[2112 + t] = acc;
    }
  } else {
    // Wc = fcw1 @ fcw2 : blocks 1..8 compute 96 rows each
    int r0 = (blockIdx.x - 1) * 96;
    for (int idx = t; idx < 96*2; idx += T) {
      int r = r0 + (idx >> 1), c = idx & 1;
      float acc = 0.f;
      for (int k = 0; k < 128; ++k) acc += fcw1[r*128 + k]*fcw2[k*2 + c];
      ws[576 + r*2 + c] = acc;
    }
  }
}

// Merged step: gbuf holds g_l = A @ h_{l-1} (FIN cols per elem).
// Thread (e, f, chunk): h_l col f = relu(g_l @ W + b) held as 12 float2 pairs
// (v_pk_fma_f32: 2 FMA/inst), BARRIER, then per row-pair A-mix (packed dot,
// horizontal add) → immediate float2 write in place.
template<int FIN, int FOUT, int SPLIT>
__device__ __forceinline__ void merged_layer(const float* __restrict__ Ag, float* gbuf,
                                             const float* Ws, const float* bs, int t) {
  constexpr int NCOLS = EPB*FOUT;       // 64/64/128/128/256/256
  constexpr int CL    = NN/SPLIT;       // 6/6/12/12/24/24
  int col = t & (NCOLS - 1);
  int i0  = __builtin_amdgcn_readfirstlane((t / NCOLS) * CL);  // wave-uniform
  int e = col / FOUT;
  int f = col & (FOUT - 1);
  const float* ib = gbuf + e*ESTR;
  // W-mix (packed): full column of h_l as 12 float2, seeded with bias
  float bf = bs[f];
  v2f hh[12];
  #pragma unroll
  for (int k = 0; k < 12; ++k) hh[k] = (v2f){bf, bf};
  #pragma unroll
  for (int fi = 0; fi < FIN; ++fi) {
    float w = Ws[fi*FOUT + f];
    v2f w2 = (v2f){w, w};
    const float4* c4 = (const float4*)(ib + fi*CSTR);
    #pragma unroll
    for (int k = 0; k < 6; ++k) {
      float4 v = c4[k];
      v2f lo = (v2f){v.x, v.y};
      v2f hi = (v2f){v.z, v.w};
      hh[2*k]   = lo*w2 + hh[2*k];     // -ffp-contract=fast → v_pk_fma_f32
      hh[2*k+1] = hi*w2 + hh[2*k+1];
    }
  }
  #pragma unroll
  for (int k = 0; k < 12; ++k) {
    hh[k].x = fmaxf(hh[k].x, 0.f);
    hh[k].y = fmaxf(hh[k].y, 0.f);
  }
  __syncthreads();           // all gbuf reads complete before in-place overwrite
  // A-mix row-pair (packed dot) → write immediately; A rows 8B-aligned (96 B)
  float* ob = gbuf + e*ESTR + f*CSTR + i0;
  #pragma unroll
  for (int ii = 0; ii < CL; ii += 2) {
    const v2f* ArA = (const v2f*)(Ag + (i0 + ii)*NN);
    const v2f* ArB = (const v2f*)(Ag + (i0 + ii + 1)*NN);
    v2f a0 = (v2f){0.f, 0.f}, a1 = (v2f){0.f, 0.f};
    #pragma unroll
    for (int j = 0; j < 12; ++j) {
      a0 = ArA[j]*hh[j] + a0;
      a1 = ArB[j]*hh[j] + a1;
    }
    *(float2*)(ob + ii) = make_float2(a0.x + a0.y, a1.x + a1.y);
  }
}

__global__ __launch_bounds__(256, 4) void gcn_main(
    const float* __restrict__ x, const float* __restrict__ ws,
    const float* __restrict__ W1, const float* __restrict__ b1,
    const float* __restrict__ W2, const float* __restrict__ b2,
    const float* __restrict__ W3, const float* __restrict__ b3,
    const float* __restrict__ W4, const float* __restrict__ b4,
    const float* __restrict__ W5, const float* __restrict__ b5,
    const float* __restrict__ W6, const float* __restrict__ b6,
    const float* __restrict__ W7, const float* __restrict__ b7,
    float* __restrict__ out) {
  __shared__ __align__(16) float gbuf[EPB*ESTR];  // 28928 B, single in-place buffer
  __shared__ float Wsh[500];                      // W1..W6; W7 read from global/L1
  __shared__ __align__(16) float bsh[88];
  int t = threadIdx.x;

  // stage layer weights/biases into LDS
  {
    const float* Wp[6] = {W1,W2,W3,W4,W5,W6};
    const float* bp[7] = {b1,b2,b3,b4,b5,b6,b7};
    const int wsz[6] = {4,16,32,64,128,256};
    const int wof[6] = {0,4,20,52,116,244};
    const int bsz[7] = {4,4,8,8,16,16,32};
    const int bof[7] = {0,4,8,16,24,40,56};
    #pragma unroll
    for (int l = 0; l < 6; ++l) {
      for (int k = t; k < wsz[l]; k += T) Wsh[wof[l] + k] = Wp[l][k];
    }
    #pragma unroll
    for (int l = 0; l < 7; ++l) {
      if (t < bsz[l]) bsh[bof[l] + t] = bp[l][t];
    }
  }
  // stage x tile into column slot 1 of each elem (col 0 gets g1 = A@x)
  {
    const float* xg = x + (size_t)blockIdx.x * (EPB*NN);
    if (t < EPB*NN/4) {
      float4 v = ((const float4*)xg)[t];
      int e = t/6, k = t - e*6;
      ((float4*)(gbuf + e*ESTR + CSTR))[k] = v;
    }
  }
  __syncthreads();

  // g1 = A @ x : 384 tasks (e, i); A rows per-lane from global (2.3 KB, L1-hot)
  {
    int e = t & 15, i = t >> 4;          // i in 0..15
    const float4* xv = (const float4*)(gbuf + e*ESTR + CSTR);
    const float4* Ar = (const float4*)(ws + i*NN);
    float acc = 0.f;
    #pragma unroll
    for (int k = 0; k < 6; ++k) {
      float4 a = Ar[k]; float4 v = xv[k];
      acc += a.x*v.x + a.y*v.y + a.z*v.z + a.w*v.w;
    }
    gbuf[e*ESTR + i] = acc;
    if (t < 128) {
      int i2 = 16 + (t >> 4);            // i in 16..23
      const float4* Ar2 = (const float4*)(ws + i2*NN);
      float acc2 = 0.f;
      #pragma unroll
      for (int k = 0; k < 6; ++k) {
        float4 a = Ar2[k]; float4 v = xv[k];
        acc2 += a.x*v.x + a.y*v.y + a.z*v.z + a.w*v.w;
      }
      gbuf[e*ESTR + i2] = acc2;
    }
  }
  __syncthreads();

  merged_layer<1, 4, 4>(ws, gbuf, Wsh+0,   bsh+0,  t); __syncthreads();
  merged_layer<4, 4, 4>(ws, gbuf, Wsh+4,   bsh+4,  t); __syncthreads();
  merged_layer<4, 8, 2>(ws, gbuf, Wsh+20,  bsh+8,  t); __syncthreads();
  merged_layer<8, 8, 2>(ws, gbuf, Wsh+52,  bsh+16, t); __syncthreads();
  merged_layer<8,16, 1>(ws, gbuf, Wsh+116, bsh+24, t); __syncthreads();
  merged_layer<16,16,1>(ws, gbuf, Wsh+244, bsh+40, t); __syncthreads();

  // L7 + composed FC + log_softmax (R5 column form, packed math):
  // hh as 12 float2 pairs; P-mix packs (p0,p1) into one float2 accumulator so
  // each h element costs one pk-fma.
  {
    const float* Wc = ws + 576;
    float bc0 = ws[2112], bc1 = ws[2113];
    #pragma unroll
    for (int r = 0; r < 2; ++r) {
      int col = t + r*T;               // 512 columns = 16 elems x 32 feats
      int e = col >> 5, f = col & 31;
      const float* ib = gbuf + e*ESTR;
      float bf = bsh[56 + f];
      v2f hh[12];
      #pragma unroll
      for (int k = 0; k < 12; ++k) hh[k] = (v2f){bf, bf};
      #pragma unroll
      for (int fi = 0; fi < 16; ++fi) {
        float w = W7[fi*32 + f];       // global, L1-cached, coalesced
        v2f w2 = (v2f){w, w};
        const float4* c4 = (const float4*)(ib + fi*CSTR);
        #pragma unroll
        for (int k = 0; k < 6; ++k) {
          float4 v = c4[k];
          v2f lo = (v2f){v.x, v.y};
          v2f hi = (v2f){v.z, v.w};
          hh[2*k]   = lo*w2 + hh[2*k];
          hh[2*k+1] = hi*w2 + hh[2*k+1];
        }
      }
      v2f p = (v2f){0.f, 0.f};         // (p0, p1)
      #pragma unroll
      for (int k = 0; k < 12; ++k) {
        float h0 = fmaxf(hh[k].x, 0.f);
        float h1 = fmaxf(hh[k].y, 0.f);
        v2f wcA = *(const v2f*)(Wc + ((2*k)*32 + f)*2);
        v2f wcB = *(const v2f*)(Wc + ((2*k + 1)*32 + f)*2);
        p = (v2f){h0, h0}*wcA + p;
        p = (v2f){h1, h1}*wcB + p;
      }
      float p0 = p.x, p1 = p.y;
      #pragma unroll
      for (int m = 1; m < 32; m <<= 1) {
        p0 += __shfl_xor(p0, m, 32);
        p1 += __shfl_xor(p1, m, 32);
      }
      if (f < 2) {
        float z0 = p0 + bc0, z1 = p1 + bc1;
        float mx = fmaxf(z0, z1);
        float lse = mx + logf(expf(z0 - mx) + expf(z1 - mx));
        int eg = blockIdx.x*EPB + e;
        out[eg*2 + f] = (f == 0 ? z0 : z1) - lse;
      }
    }
  }
}

extern "C" void kernel_launch(void* const* d_in, const int* in_sizes, int n_in,
                              void* d_out, int out_size, void* d_ws, size_t ws_size,
                              hipStream_t stream) {
  const float* x    = (const float*)d_in[0];
  const int*   ei   = (const int*)  d_in[1];
  const float* W1   = (const float*)d_in[2];  const float* b1 = (const float*)d_in[3];
  const float* W2   = (const float*)d_in[4];  const float* b2 = (const float*)d_in[5];
  const float* W3   = (const float*)d_in[6];  const float* b3 = (const float*)d_in[7];
  const float* W4   = (const float*)d_in[8];  const float* b4 = (const float*)d_in[9];
  const float* W5   = (const float*)d_in[10]; const float* b5 = (const float*)d_in[11];
  const float* W6   = (const float*)d_in[12]; const float* b6 = (const float*)d_in[13];
  const float* W7   = (const float*)d_in[14]; const float* b7 = (const float*)d_in[15];
  const float* fcw1 = (const float*)d_in[16]; const float* fcb1 = (const float*)d_in[17];
  const float* fcw2 = (const float*)d_in[18]; const float* fcb2 = (const float*)d_in[19];
  float* out = (float*)d_out;
  float* ws  = (float*)d_ws;
  int ec = in_sizes[1] / 2;        // 96 edges
  int B  = in_sizes[0] / NN;       // 32768

  hipLaunchKernelGGL(prep_kernel, dim3(9), dim3(T), 0, stream,
                     ei, ec, fcw1, fcb1, fcw2, fcb2, ws);
  hipLaunchKernelGGL(gcn_main, dim3(B/EPB), dim3(T), 0, stream,
                     x, ws, W1,b1, W2,b2, W3,b3, W4,b4, W5,b5, W6,b6, W7,b7, out);
}